// Round 12
// baseline (4631.313 us; speedup 1.0000x reference)
//
#include <hip/hip_runtime.h>
#include <hip/hip_bf16.h>

typedef short s16x8 __attribute__((ext_vector_type(8)));
typedef int   i32x4 __attribute__((ext_vector_type(4)));
typedef unsigned u32x2 __attribute__((ext_vector_type(2)));
typedef float f32x4 __attribute__((ext_vector_type(4)));
typedef float f32x2 __attribute__((ext_vector_type(2)));

#define T_STEPS 1024
#define BATCH   128
#define DIN     256
#define DH      256
#define NWG     64     // 8 batch-groups (x16 rows) x 8 col-slices (x32 h-cols)
#define NTHREADS 256

static __device__ __forceinline__ short f2bf(float f){ return __builtin_bit_cast(short,(__bf16)f); }
static __device__ __forceinline__ float sigf(float x){ return 1.f/(1.f+__expf(-x)); }
static __device__ __forceinline__ float tanhfast(float x){ return 1.f-2.f/(1.f+__expf(2.f*x)); }

// ---- MALL-coherent primitives (sc0 sc1 = bypass L1+L2; proven r3..r11) ----
static __device__ __forceinline__ i32x4 ld16_cc(const void* p){
  i32x4 r; asm volatile("global_load_dwordx4 %0, %1, off sc0 sc1" : "=v"(r) : "v"(p) : "memory"); return r;
}
static __device__ __forceinline__ unsigned ld4i_cc(const void* p){   // issue-only
  unsigned r; asm volatile("global_load_dword %0, %1, off sc0 sc1" : "=v"(r) : "v"(p) : "memory"); return r;
}
static __device__ __forceinline__ unsigned ld4_cc(const void* p){
  unsigned r; asm volatile("global_load_dword %0, %1, off sc0 sc1\ns_waitcnt vmcnt(0)" : "=v"(r) : "v"(p) : "memory"); return r;
}
static __device__ __forceinline__ void st4_cc(void* p, unsigned v){
  asm volatile("global_store_dword %0, %1, off sc0 sc1" :: "v"(p), "v"(v) : "memory");
}
static __device__ __forceinline__ void st8t_cc(void* p, u32x2 v){
  asm volatile("global_store_dwordx2 %0, %1, off sc0 sc1" :: "v"(p), "v"(v) : "memory");
}
static __device__ __forceinline__ void st8_p(void* p, f32x2 v){
  asm volatile("global_store_dwordx2 %0, %1, off" :: "v"(p), "v"(v) : "memory");
}
#define VM0 do { asm volatile("s_waitcnt vmcnt(0)" ::: "memory"); \
  __builtin_amdgcn_sched_barrier(0); } while (0)

static __device__ __forceinline__ s16x8 cvt8(f32x4 a, f32x4 b){
  s16x8 r;
  r[0]=f2bf(a[0]); r[1]=f2bf(a[1]); r[2]=f2bf(a[2]); r[3]=f2bf(a[3]);
  r[4]=f2bf(b[0]); r[5]=f2bf(b[1]); r[6]=f2bf(b[2]); r[7]=f2bf(b[3]);
  return r;
}

// =============== PRIMARY: flagless sentinel-poll exchange (tagged h) ===============
__global__ __launch_bounds__(NTHREADS, 1)
void lstm_v12(const float* __restrict__ X,
              const float* __restrict__ Wf, const float* __restrict__ bfv,
              const float* __restrict__ Wi, const float* __restrict__ biv,
              const float* __restrict__ Wg, const float* __restrict__ bgv,
              const float* __restrict__ Wo, const float* __restrict__ bov,
              float* __restrict__ out,
              unsigned* __restrict__ htag)     // [2][128][256] u32: (tag<<16)|bf16
{
  const int bid = blockIdx.x;
  const int g   = bid & 7;        // batch group (rows g*16 .. g*16+15)
  const int csl = bid >> 3;       // column slice: h-cols [32*csl, 32*csl+32)
  const int tid = threadIdx.x;
  const int lane = tid & 63, wv = tid >> 6;
  const int grp = lane >> 4, l15 = lane & 15;
  const int r0 = g * 16;

  __shared__ short a_lds[2 * 32 * 16 * 8];   // x A-frag staging, dbuf, 16 KB
  __shared__ float elds[16 * 132];           // cross-wave epilogue bounce

  // ---- weights -> registers: bfr[n2][kk], kk<8 = x-part, kk>=8 = h-part ----
  s16x8 bfr[2][16];
  {
    const float* Wm[4] = {Wf, Wi, Wg, Wo};
    const int gate = l15 >> 2, jj = l15 & 3;
    const float* Wsrc = Wm[gate];
#pragma unroll
    for (int n2 = 0; n2 < 2; ++n2) {
      const int hc = csl * 32 + (wv * 2 + n2) * 4 + jj;
#pragma unroll
      for (int kk = 0; kk < 16; ++kk) {
        const float* p = Wsrc + (size_t)(kk * 32 + grp * 8) * DH + hc;
        s16x8 f;
#pragma unroll
        for (int s = 0; s < 8; ++s) f[s] = f2bf(p[(size_t)s * DH]);
        bfr[n2][kk] = f;
      }
    }
  }

  // epilogue roles: row r0+erow, local col pair {2*j2, 2*j2+1}
  const int erow = tid >> 4;
  const int j2   = tid & 15;
  const int ntl  = j2 >> 1;
  const int jjl  = (j2 & 1) * 2;
  float bia[4][2];
  {
    const float* Bv[4] = {bfv, biv, bgv, bov};
#pragma unroll
    for (int q = 0; q < 4; ++q) {
      bia[q][0] = Bv[q][csl * 32 + 2 * j2];
      bia[q][1] = Bv[q][csl * 32 + 2 * j2 + 1];
    }
  }

  // X staging roles
  const int xrow = tid & 15, xseg = tid >> 4;
  f32x4 xp0, xp1, xp2, xp3;
  {
    const float* xs = X + (size_t)(r0 + xrow) * DIN + xseg * 16;
    s16x8 lo = cvt8(*(const f32x4*)xs, *(const f32x4*)(xs + 4));
    s16x8 hi = cvt8(*(const f32x4*)(xs + 8), *(const f32x4*)(xs + 12));
    *(s16x8*)&a_lds[((2 * xseg + 0) * 16 + xrow) * 8] = lo;
    *(s16x8*)&a_lds[((2 * xseg + 1) * 16 + xrow) * 8] = hi;
    const float* xn = X + ((size_t)1 * BATCH + r0 + xrow) * DIN + xseg * 16;
    xp0 = *(const f32x4*)xn;       xp1 = *(const f32x4*)(xn + 4);
    xp2 = *(const f32x4*)(xn + 8); xp3 = *(const f32x4*)(xn + 12);
  }
  __syncthreads();

  float cs0 = 0.f, cs1 = 0.f, h0s = 0.f, h1s = 0.f;

  for (int t = 0; t < T_STEPS; ++t) {
    const unsigned tte = (unsigned)t << 16;
    const unsigned* hb = htag + (size_t)(t & 1) * (BATCH * DH)
                       + (size_t)(r0 + l15) * DH + grp * 8;

    // ---- 1. sentinel poll: 8 dwords, one per producer slice, at addresses
    //         this lane will consume (row l15, col q*32+grp*8). The signal IS
    //         the data: it cannot lead the store it certifies. ----
    {
      int guard = 1 << 16;
      while (1) {
        unsigned s[8];
#pragma unroll
        for (int q = 0; q < 8; ++q) s[q] = ld4i_cc(hb + q * 32);
        VM0;
        unsigned bad = 0;
#pragma unroll
        for (int q = 0; q < 8; ++q) bad |= (s[q] ^ tte);
        bad &= 0xFFFF0000u;
        if (__all((int)(bad == 0))) break;
        if (--guard < 0) break;
      }
    }

    // ---- 2. issue full tagged h(t) loads ----
    i32x4 hraw[16];
#pragma unroll
    for (int q = 0; q < 8; ++q) {
      hraw[2 * q]     = ld16_cc(hb + q * 32);
      hraw[2 * q + 1] = ld16_cc(hb + q * 32 + 4);
    }

    // ---- 3. stage x(t+1) regs -> a_lds[(t+1)&1] ----
    {
      short* ab = a_lds + ((t + 1) & 1) * (32 * 16 * 8);
      s16x8 lo = cvt8(xp0, xp1), hi = cvt8(xp2, xp3);
      *(s16x8*)&ab[((2 * xseg + 0) * 16 + xrow) * 8] = lo;
      *(s16x8*)&ab[((2 * xseg + 1) * 16 + xrow) * 8] = hi;
    }

    // ---- 4. x-part MFMAs from a_lds[t&1] (covers h-load RT) ----
    const short* ar = a_lds + (t & 1) * (32 * 16 * 8);
    f32x4 acc0 = {0.f,0.f,0.f,0.f}, acc1 = {0.f,0.f,0.f,0.f};
#pragma unroll
    for (int kk = 0; kk < 8; ++kk) {
      s16x8 a = *(const s16x8*)&ar[((kk * 4 + grp) * 16 + l15) * 8];
      acc0 = __builtin_amdgcn_mfma_f32_16x16x32_bf16(a, bfr[0][kk], acc0, 0, 0, 0);
      acc1 = __builtin_amdgcn_mfma_f32_16x16x32_bf16(a, bfr[1][kk], acc1, 0, 0, 0);
    }

    // ---- 5. validate all tags; retry residual skew (rare) ----
    VM0;
    {
      int guard = 1 << 14;
      while (1) {
        unsigned bad = 0;
#pragma unroll
        for (int i = 0; i < 16; ++i)
          bad |= (unsigned)(hraw[i][0] ^ (int)tte) | (unsigned)(hraw[i][1] ^ (int)tte)
               | (unsigned)(hraw[i][2] ^ (int)tte) | (unsigned)(hraw[i][3] ^ (int)tte);
        bad &= 0xFFFF0000u;
        if (__all((int)(bad == 0))) break;
        if (--guard < 0) break;
#pragma unroll
        for (int q = 0; q < 8; ++q) {
          hraw[2 * q]     = ld16_cc(hb + q * 32);
          hraw[2 * q + 1] = ld16_cc(hb + q * 32 + 4);
        }
        VM0;
      }
    }

    // ---- 6. unpack (v_perm) + h-part MFMAs ----
#pragma unroll
    for (int q = 0; q < 8; ++q) {
      i32x4 hp;
      hp[0] = (int)__builtin_amdgcn_perm((unsigned)hraw[2*q][1],   (unsigned)hraw[2*q][0],   0x05040100u);
      hp[1] = (int)__builtin_amdgcn_perm((unsigned)hraw[2*q][3],   (unsigned)hraw[2*q][2],   0x05040100u);
      hp[2] = (int)__builtin_amdgcn_perm((unsigned)hraw[2*q+1][1], (unsigned)hraw[2*q+1][0], 0x05040100u);
      hp[3] = (int)__builtin_amdgcn_perm((unsigned)hraw[2*q+1][3], (unsigned)hraw[2*q+1][2], 0x05040100u);
      s16x8 ah = __builtin_bit_cast(s16x8, hp);
      acc0 = __builtin_amdgcn_mfma_f32_16x16x32_bf16(ah, bfr[0][8 + q], acc0, 0, 0, 0);
      acc1 = __builtin_amdgcn_mfma_f32_16x16x32_bf16(ah, bfr[1][8 + q], acc1, 0, 0, 0);
    }

    // ---- 7. cross-wave epilogue; B1 = lgkm drain + raw barrier (no vm drain) ----
#pragma unroll
    for (int rr = 0; rr < 4; ++rr) {
      elds[(grp * 4 + rr) * 132 + (wv * 2 + 0) * 16 + l15] = acc0[rr];
      elds[(grp * 4 + rr) * 132 + (wv * 2 + 1) * 16 + l15] = acc1[rr];
    }
    asm volatile("s_waitcnt lgkmcnt(0)" ::: "memory");
    __builtin_amdgcn_sched_barrier(0);
    __builtin_amdgcn_s_barrier();                       // B1
    __builtin_amdgcn_sched_barrier(0);

    const float* ez = &elds[erow * 132 + ntl * 16];
    float h0, h1;
    {
      float zf = ez[0 + jjl] + bia[0][0], zi = ez[4 + jjl] + bia[1][0];
      float zg = ez[8 + jjl] + bia[2][0], zo = ez[12 + jjl] + bia[3][0];
      float cn = sigf(zf) * cs0 + sigf(zi) * tanhfast(zg);
      h0 = sigf(zo) * tanhfast(cn); cs0 = cn; h0s = h0;
    }
    {
      float zf = ez[1 + jjl] + bia[0][1], zi = ez[5 + jjl] + bia[1][1];
      float zg = ez[9 + jjl] + bia[2][1], zo = ez[13 + jjl] + bia[3][1];
      float cn = sigf(zf) * cs1 + sigf(zi) * tanhfast(zg);
      h1 = sigf(zo) * tanhfast(cn); cs1 = cn; h1s = h1;
    }

    // ---- 8. tagged h(t+1) store — producer tail ENDS here (no ack/flag/barrier) ----
    const int rowg = r0 + erow;
    {
      const unsigned ttw = (unsigned)(t + 1) << 16;
      u32x2 hp2;
      hp2[0] = (unsigned)(unsigned short)f2bf(h0) | ttw;
      hp2[1] = (unsigned)(unsigned short)f2bf(h1) | ttw;
      st8t_cc(htag + (size_t)((t + 1) & 1) * (BATCH * DH)
              + (size_t)rowg * DH + csl * 32 + 2 * j2, hp2);
    }

    // ---- 9. shadow: out store (fp32), x(t+2) prefetch ----
    {
      f32x2 ov; ov[0] = h0; ov[1] = h1;
      st8_p(out + ((size_t)t * BATCH + rowg) * DH + csl * 32 + 2 * j2, ov);
    }
    {
      const int tp = (t + 2 < T_STEPS) ? t + 2 : T_STEPS - 1;
      const float* xs = X + ((size_t)tp * BATCH + r0 + xrow) * DIN + xseg * 16;
      xp0 = *(const f32x4*)xs;       xp1 = *(const f32x4*)(xs + 4);
      xp2 = *(const f32x4*)(xs + 8); xp3 = *(const f32x4*)(xs + 12);
    }
  }

  // ---- final hx, cx (fp32, from registers; buffers in d_ws -> no aliasing) ----
  {
    const size_t base = (size_t)T_STEPS * BATCH * DH;
    const size_t idx  = (size_t)(r0 + erow) * DH + csl * 32 + 2 * j2;
    out[base + idx]     = h0s;
    out[base + idx + 1] = h1s;
    out[base + BATCH * DH + idx]     = cs0;
    out[base + BATCH * DH + idx + 1] = cs1;
  }
}

// =============== FALLBACK (r10 engine, buffers in d_out tail; ws too small) ===============
static __device__ __forceinline__ i32x4 ld16f_cc(const void* p){
  i32x4 r; asm volatile("global_load_dwordx4 %0, %1, off sc0 sc1" : "=v"(r) : "v"(p) : "memory"); return r;
}
__global__ __launch_bounds__(NTHREADS, 1)
void lstm_fb(const float* __restrict__ X,
             const float* __restrict__ Wf, const float* __restrict__ bfv,
             const float* __restrict__ Wi, const float* __restrict__ biv,
             const float* __restrict__ Wg, const float* __restrict__ bgv,
             const float* __restrict__ Wo, const float* __restrict__ bov,
             float* __restrict__ out,
             unsigned short* __restrict__ hbuf,
             unsigned int* __restrict__ flags)
{
  const int bid = blockIdx.x;
  const int g   = bid & 7;
  const int csl = bid >> 3;
  const int tid = threadIdx.x;
  const int lane = tid & 63, wv = tid >> 6;
  const int grp = lane >> 4, l15 = lane & 15;
  const int r0 = g * 16;

  __shared__ short a_lds[2 * 32 * 16 * 8];
  __shared__ float elds[4 * 16 * 36];

  s16x8 bfr[2][16];
  {
    const float* Wm[4] = {Wf, Wi, Wg, Wo};
    const int gate = l15 >> 2, jj = l15 & 3;
    const float* Wsrc = Wm[gate];
#pragma unroll
    for (int n2 = 0; n2 < 2; ++n2) {
      const int hc = csl * 32 + (wv * 2 + n2) * 4 + jj;
#pragma unroll
      for (int kk = 0; kk < 16; ++kk) {
        const float* p = Wsrc + (size_t)(kk * 32 + grp * 8) * DH + hc;
        s16x8 f;
#pragma unroll
        for (int s = 0; s < 8; ++s) f[s] = f2bf(p[(size_t)s * DH]);
        bfr[n2][kk] = f;
      }
    }
  }
  const int colg = csl * 32 + wv * 8 + 2 * grp;
  float bia[4][2];
  {
    const float* Bv[4] = {bfv, biv, bgv, bov};
#pragma unroll
    for (int q = 0; q < 4; ++q) { bia[q][0] = Bv[q][colg]; bia[q][1] = Bv[q][colg + 1]; }
  }
  const int xrow = tid & 15, xseg = tid >> 4;
  f32x4 xp0, xp1, xp2, xp3;
  {
    const float* xs = X + (size_t)(r0 + xrow) * DIN + xseg * 16;
    s16x8 lo = cvt8(*(const f32x4*)xs, *(const f32x4*)(xs + 4));
    s16x8 hi = cvt8(*(const f32x4*)(xs + 8), *(const f32x4*)(xs + 12));
    *(s16x8*)&a_lds[((2 * xseg + 0) * 16 + xrow) * 8] = lo;
    *(s16x8*)&a_lds[((2 * xseg + 1) * 16 + xrow) * 8] = hi;
    const float* xn = X + ((size_t)1 * BATCH + r0 + xrow) * DIN + xseg * 16;
    xp0 = *(const f32x4*)xn;       xp1 = *(const f32x4*)(xn + 4);
    xp2 = *(const f32x4*)(xn + 8); xp3 = *(const f32x4*)(xn + 12);
  }
  __syncthreads();

  unsigned* myflag = flags + (g * 32 + csl * 4 + wv);
  const unsigned* pollp = flags + (g * 32 + (lane & 31));
  float* eldsw = &elds[wv * 16 * 36];
  float cs0 = 0.f, cs1 = 0.f, h0s = 0.f, h1s = 0.f;

  for (int t = 0; t < T_STEPS; ++t) {
    while (1) {
      unsigned v = ld4_cc(pollp);
      if (__all((int)(v >= (unsigned)t))) break;
    }
    __builtin_amdgcn_sched_barrier(0);
    const unsigned short* hr = hbuf + (size_t)(t & 1) * (BATCH * DH)
                             + (size_t)(r0 + l15) * DH + grp * 8;
    i32x4 hraw[8];
#pragma unroll
    for (int q = 0; q < 8; ++q) hraw[q] = ld16f_cc(hr + q * 32);
    {
      short* ab = a_lds + ((t + 1) & 1) * (32 * 16 * 8);
      s16x8 lo = cvt8(xp0, xp1), hi = cvt8(xp2, xp3);
      *(s16x8*)&ab[((2 * xseg + 0) * 16 + xrow) * 8] = lo;
      *(s16x8*)&ab[((2 * xseg + 1) * 16 + xrow) * 8] = hi;
    }
    const short* ar = a_lds + (t & 1) * (32 * 16 * 8);
    f32x4 acc0 = {0.f,0.f,0.f,0.f}, acc1 = {0.f,0.f,0.f,0.f};
#pragma unroll
    for (int kk = 0; kk < 8; ++kk) {
      s16x8 a = *(const s16x8*)&ar[((kk * 4 + grp) * 16 + l15) * 8];
      acc0 = __builtin_amdgcn_mfma_f32_16x16x32_bf16(a, bfr[0][kk], acc0, 0, 0, 0);
      acc1 = __builtin_amdgcn_mfma_f32_16x16x32_bf16(a, bfr[1][kk], acc1, 0, 0, 0);
    }
    VM0;
#pragma unroll
    for (int q = 0; q < 8; ++q) {
      s16x8 ah = __builtin_bit_cast(s16x8, hraw[q]);
      acc0 = __builtin_amdgcn_mfma_f32_16x16x32_bf16(ah, bfr[0][8 + q], acc0, 0, 0, 0);
      acc1 = __builtin_amdgcn_mfma_f32_16x16x32_bf16(ah, bfr[1][8 + q], acc1, 0, 0, 0);
    }
#pragma unroll
    for (int rr = 0; rr < 4; ++rr) {
      eldsw[(grp * 4 + rr) * 36 + l15]      = acc0[rr];
      eldsw[(grp * 4 + rr) * 36 + 16 + l15] = acc1[rr];
    }
    asm volatile("s_waitcnt lgkmcnt(0)" ::: "memory");
    __builtin_amdgcn_sched_barrier(0);
    float z0[4], z1[4];
    const int hc0 = 2 * grp, hc1 = 2 * grp + 1;
#pragma unroll
    for (int q = 0; q < 4; ++q) {
      z0[q] = eldsw[l15 * 36 + ((hc0 >> 2) << 4) + 4 * q + (hc0 & 3)];
      z1[q] = eldsw[l15 * 36 + ((hc1 >> 2) << 4) + 4 * q + (hc1 & 3)];
    }
    {
      float zf = z0[0] + bia[0][0], zi = z0[1] + bia[1][0];
      float zg = z0[2] + bia[2][0], zo = z0[3] + bia[3][0];
      cs0 = sigf(zf) * cs0 + sigf(zi) * tanhfast(zg);
      h0s = sigf(zo) * tanhfast(cs0);
    }
    {
      float zf = z1[0] + bia[0][1], zi = z1[1] + bia[1][1];
      float zg = z1[2] + bia[2][1], zo = z1[3] + bia[3][1];
      cs1 = sigf(zf) * cs1 + sigf(zi) * tanhfast(zg);
      h1s = sigf(zo) * tanhfast(cs1);
    }
    const int row = r0 + l15;
    {
      unsigned hpk = (unsigned)(unsigned short)f2bf(h0s)
                   | ((unsigned)(unsigned short)f2bf(h1s) << 16);
      st4_cc(hbuf + (size_t)((t + 1) & 1) * (BATCH * DH)
             + (size_t)row * DH + colg, hpk);
      f32x2 ov; ov[0] = h0s; ov[1] = h1s;
      st8_p(out + ((size_t)t * BATCH + row) * DH + colg, ov);
    }
    asm volatile("s_waitcnt vmcnt(1)" ::: "memory");
    if (lane == 0) st4_cc(myflag, (unsigned)(t + 1));
    {
      const int tp = (t + 2 < T_STEPS) ? t + 2 : T_STEPS - 1;
      const float* xs = X + ((size_t)tp * BATCH + r0 + xrow) * DIN + xseg * 16;
      xp0 = *(const f32x4*)xs;       xp1 = *(const f32x4*)(xs + 4);
      xp2 = *(const f32x4*)(xs + 8); xp3 = *(const f32x4*)(xs + 12);
    }
  }
  {
    const unsigned* fp = flags + tid;
    while (ld4_cc(fp) < (unsigned)T_STEPS) __builtin_amdgcn_s_sleep(1);
    __syncthreads();
  }
  {
    const size_t base = (size_t)T_STEPS * BATCH * DH;
    const size_t idx  = (size_t)(r0 + l15) * DH + colg;
    out[base + idx]     = h0s;
    out[base + idx + 1] = h1s;
    out[base + BATCH * DH + idx]     = cs0;
    out[base + BATCH * DH + idx + 1] = cs1;
  }
}

extern "C" void kernel_launch(void* const* d_in, const int* in_sizes, int n_in,
                              void* d_out, int out_size, void* d_ws, size_t ws_size,
                              hipStream_t stream) {
  const float* X   = (const float*)d_in[0];
  const float* Wf  = (const float*)d_in[1];
  const float* bf_ = (const float*)d_in[2];
  const float* Wi  = (const float*)d_in[3];
  const float* bi_ = (const float*)d_in[4];
  const float* Wg  = (const float*)d_in[5];
  const float* bg_ = (const float*)d_in[6];
  const float* Wo  = (const float*)d_in[7];
  const float* bo_ = (const float*)d_in[8];
  float* out = (float*)d_out;

  const size_t tagbytes = (size_t)2 * BATCH * DH * 4;   // 262144
  if (ws_size >= tagbytes) {
    unsigned* htag = (unsigned*)d_ws;
    hipMemsetAsync(d_ws, 0, tagbytes, stream);          // tag 0 == t=0, h=0
    lstm_v12<<<NWG, NTHREADS, 0, stream>>>(X, Wf, bf_, Wi, bi_, Wg, bg_,
                                           Wo, bo_, out, htag);
    return;
  }
  // fallback: untagged r10 engine, buffers in d_out tail
  unsigned char* tail = (unsigned char*)d_out + (size_t)T_STEPS * BATCH * DH * 4;
  unsigned short* hbuf = (unsigned short*)tail;
  unsigned int* flags  = (unsigned int*)(tail + 131072);
  hipMemsetAsync(tail, 0, 131072 + 1024, stream);
  lstm_fb<<<NWG, NTHREADS, 0, stream>>>(X, Wf, bf_, Wi, bi_, Wg, bg_,
                                        Wo, bo_, out, hbuf, flags);
}